// Round 1
// baseline (811.929 us; speedup 1.0000x reference)
//
#include <hip/hip_runtime.h>

typedef unsigned short u16;
typedef unsigned int u32;
typedef __bf16 bf16x8 __attribute__((ext_vector_type(8)));
typedef float f32x4 __attribute__((ext_vector_type(4)));
typedef unsigned int u32x4 __attribute__((ext_vector_type(4)));

// Problem constants (B=8, D=128, H=W=256, border=16, cell=8)
#define NS 6272              // samples per image set (8*28*28)
#define NCOLS 6285           // 1 + 12 + 6272
#define SCORES_OFF 0LL
#define LABELS_OFF 39419520LL
#define MASK_OFF   78839040LL
#define QLT_OFF    78845312LL

#define ZBLK 2048            // zeroing blocks appended to K1 grid
#define LBL_F4 9854880       // NS*NCOLS/4 (labels region in float4s, exact)

// pos offsets: (i,j), i outer loop, j inner, i^2+j^2<=9. pos_off[0]=i -> x, pos_off[1]=j -> y
__constant__ int POSX[29] = {-3,-2,-2,-2,-2,-2,-1,-1,-1,-1,-1, 0,0,0,0,0,0,0, 1,1,1,1,1, 2,2,2,2,2, 3};
__constant__ int POSY[29] = { 0,-2,-1, 0, 1, 2,-2,-1, 0, 1, 2,-3,-2,-1,0,1,2,3,-2,-1,0,1,2,-2,-1,0,1,2, 0};
// neg offsets: step 2, 49<=i^2+j^2<=64
__constant__ int NEGX[12] = {-8,-6,-6,-4,-4, 0,0, 4,4, 6,6, 8};
__constant__ int NEGY[12] = { 0,-4, 4,-6, 6,-8,8,-6,6,-4,4, 0};

__device__ inline u16 f2bf(float f) {
  u32 u = __float_as_uint(f);
  u = (u + 0x7FFFu + ((u >> 16) & 1u)) >> 16;  // RNE (inputs have no NaN)
  return (u16)u;
}

// K1: one wave per 8x8 cell -> butterfly argmax (first-occurrence, all lanes get
// result) -> fused descriptor gather (2 channels/lane) + per-sample bookkeeping.
// Blocks >= 3136 instead zero the labels output region (replaces hipMemsetAsync;
// store-BW work co-runs with the latency-bound gathers).
// NOTE the reference's coordinate SWAP: _sample returns (b,x,y) unpacked as
// (b, y1, x1) -> all gathers at sample points use row=X (W-coord of max),
// col=Y (H-coord of max).
__global__ __launch_bounds__(256) void sample_gather_zero_kernel(
    const float* __restrict__ det1, const float* __restrict__ det2,
    const float* __restrict__ aflow, const float* __restrict__ qlt1,
    const float* __restrict__ des1, const float* __restrict__ des2,
    int* __restrict__ x2a, int* __restrict__ y2a,
    int* __restrict__ xd, int* __restrict__ yd,
    float* __restrict__ qlt1v,
    float* __restrict__ A_f32, u16* __restrict__ A_bf16, u16* __restrict__ D_bf16,
    float* __restrict__ out) {
  if (blockIdx.x >= 3136) {
    // zero labels region, nontemporal float4 streaming stores
    size_t t = (size_t)(blockIdx.x - 3136) * 256 + threadIdx.x;
    f32x4* p = (f32x4*)(out + LABELS_OFF);
    f32x4 z = {0.0f, 0.0f, 0.0f, 0.0f};
    for (size_t i = t; i < (size_t)LBL_F4; i += (size_t)ZBLK * 256)
      __builtin_nontemporal_store(z, p + i);
    return;
  }
  int isDet2 = (blockIdx.x >= 1568);
  int cell = (blockIdx.x - (isDet2 ? 1568 : 0)) * 4 + (threadIdx.x >> 6);
  int l = threadIdx.x & 63;
  int b = cell / 784, rem = cell % 784;
  int cy = rem / 28, cx = rem % 28;
  int y = 16 + cy * 8 + (l >> 3), x = 16 + cx * 8 + (l & 7);
  const float* det = isDet2 ? det2 : det1;
  float v = det[((size_t)b << 16) + (y << 8) + x];
  int idx = l;
  // butterfly: every lane ends with (max, lowest index on ties)
  #pragma unroll
  for (int off = 1; off < 64; off <<= 1) {
    float ov = __shfl_xor(v, off);
    int oi = __shfl_xor(idx, off);
    if (ov > v || (ov == v && oi < idx)) { v = ov; idx = oi; }
  }
  int ii = idx >> 3, jj = idx & 7;
  int X = 16 + cx * 8 + jj;   // W-coordinate of cell max
  int Y = 16 + cy * 8 + ii;   // H-coordinate of cell max
  if (!isDet2) {
    if (l == 0) {
      // reference: y1 = X (row index), x1 = Y (col index)
      float ax = aflow[((size_t)(b * 2) << 16) + (X << 8) + Y];
      float ay = aflow[((size_t)(b * 2 + 1) << 16) + (X << 8) + Y];
      int xx = (int)(ax + 0.5f);   // trunc after +0.5, matches astype(int32)
      int yy = (int)(ay + 0.5f);
      x2a[cell] = xx; y2a[cell] = yy;
      out[MASK_OFF + cell] = (xx >= 0 && yy >= 0 && xx < 256 && yy < 256) ? 1.0f : 0.0f;
      qlt1v[cell] = qlt1[((size_t)b << 16) + (X << 8) + Y];
    }
    // gather des1[b, :, X, Y]: 2 channels per lane (c = l and c = l+64)
    const float* p = des1 + (((size_t)b * 128) << 16) + (X << 8) + Y;
    float v0 = p[(size_t)l << 16];
    float v1 = p[(size_t)(l + 64) << 16];
    A_f32[(size_t)cell * 128 + l] = v0;
    A_f32[(size_t)cell * 128 + l + 64] = v1;
    A_bf16[(size_t)cell * 128 + l] = f2bf(v0);
    A_bf16[(size_t)cell * 128 + l + 64] = f2bf(v1);
  } else {
    if (l == 0) {
      // reference: yd = X (row index), xd = Y (col index)
      yd[cell] = X; xd[cell] = Y;
    }
    // distr = des2[bd, :, yd, xd]
    const float* p = des2 + (((size_t)b * 128) << 16) + (X << 8) + Y;
    D_bf16[(size_t)cell * 128 + l] = f2bf(p[(size_t)l << 16]);
    D_bf16[(size_t)cell * 128 + l + 64] = f2bf(p[(size_t)(l + 64) << 16]);
  }
}

// K2: heterogeneous blocks.
//  blockIdx.x <  1568 : small-scores (pos/neg candidates, one wave per sample)
//                       + labels col0 = 1 + qlt output.
//  blockIdx.x >= 1568 : dscores GEMM tile (bf16 MFMA 16x16x32, 128x128 tile,
//                       K=128 staged once in LDS), fused distance-mask epilogue.
// Small blocks are latency-bound (scattered L3 reads), GEMM blocks are
// MFMA+store-BW bound -> co-scheduling hides both.
__global__ __launch_bounds__(256, 2) void scores_kernel(
    const u16* __restrict__ A, const u16* __restrict__ Bm,
    const float* __restrict__ des2, const float* __restrict__ qlt2,
    const float* __restrict__ A_f32, const float* __restrict__ qlt1v,
    const int* __restrict__ x2a, const int* __restrict__ y2a,
    const int* __restrict__ xd, const int* __restrict__ yd,
    float* __restrict__ out) {
  __shared__ u16 As[128 * 136];  // +8 bf16 pad per row
  __shared__ u16 Bs[128 * 136];
  int tid = threadIdx.x;
  if (blockIdx.x < 1568) {
    // ---- small scores: lane<29 -> pos candidate, 29..40 -> neg candidate ----
    int n = blockIdx.x * 4 + (tid >> 6);
    int l = tid & 63;
    int b = n / 784;
    int x2 = x2a[n], y2 = y2a[n];
    int ox = 0, oy = 0;
    if (l < 29) { ox = POSX[l]; oy = POSY[l]; }
    else if (l < 41) { ox = NEGX[l - 29]; oy = NEGY[l - 29]; }
    int xc = min(max(x2 + ox, 0), 255);   // col (W) index
    int yc = min(max(y2 + oy, 0), 255);   // row (H) index
    const float* d2 = des2 + ((size_t)b << 23) + ((size_t)yc << 8) + xc;
    const float* ar = A_f32 + (size_t)n * 128;
    float acc = 0.0f;
    #pragma unroll 16
    for (int c = 0; c < 128; ++c) acc += ar[c] * d2[(size_t)c << 16];
    if (l >= 29 && l < 41) out[SCORES_OFF + (size_t)n * NCOLS + 1 + (l - 29)] = acc;
    float v = (l < 29) ? acc : -1e30f;
    int idx = l;
    #pragma unroll
    for (int off = 32; off; off >>= 1) {
      float ov = __shfl_down(v, off);
      int oi = __shfl_down(idx, off);
      if (ov > v || (ov == v && oi < idx)) { v = ov; idx = oi; }
    }
    if (l == 0) {
      out[SCORES_OFF + (size_t)n * NCOLS] = v;
      out[LABELS_OFF + (size_t)n * NCOLS] = 1.0f;   // labels col0 (region zeroed in K1)
      int sx = min(max(x2 + POSX[idx], 0), 255);
      int sy = min(max(y2 + POSY[idx], 0), 255);
      float q = (qlt1v[n] + qlt2[((size_t)b << 16) + (sy << 8) + sx]) * 0.5f;
      out[QLT_OFF + n] = q;
    }
    return;
  }
  // ---- dscores GEMM: C[n,m] = sum_k A[n,k]*D[m,k] ----
  int bi = blockIdx.x - 1568;
  int R = bi / 49, C = bi % 49;
  const u32x4* gA = (const u32x4*)(A + (size_t)R * 16384);
  const u32x4* gB = (const u32x4*)(Bm + (size_t)C * 16384);
  #pragma unroll
  for (int p = 0; p < 8; ++p) {
    int i = tid + p * 256;
    int r = i >> 4, kc = (i & 15) * 8;
    *(u32x4*)&As[r * 136 + kc] = gA[i];
    *(u32x4*)&Bs[r * 136 + kc] = gB[i];
  }
  __syncthreads();
  int l = tid & 63, w = tid >> 6;
  int lr = l & 15, lq = l >> 4;
  int wr = (w & 1) * 64, wc = (w >> 1) * 64;
  f32x4 acc[4][4] = {};
  #pragma unroll
  for (int kk = 0; kk < 4; ++kk) {
    bf16x8 af[4], bfr[4];
    #pragma unroll
    for (int t = 0; t < 4; ++t) {
      af[t]  = *(const bf16x8*)&As[(wr + t * 16 + lr) * 136 + kk * 32 + lq * 8];
      bfr[t] = *(const bf16x8*)&Bs[(wc + t * 16 + lr) * 136 + kk * 32 + lq * 8];
    }
    #pragma unroll
    for (int tr = 0; tr < 4; ++tr)
      #pragma unroll
      for (int tc = 0; tc < 4; ++tc)
        acc[tr][tc] = __builtin_amdgcn_mfma_f32_16x16x32_bf16(af[tr], bfr[tc], acc[tr][tc], 0, 0, 0);
  }
  #pragma unroll
  for (int tr = 0; tr < 4; ++tr) {
    int rows[4], rx[4], ry[4], rb[4];
    #pragma unroll
    for (int r = 0; r < 4; ++r) {
      int row = R * 128 + wr + tr * 16 + lq * 4 + r;
      rows[r] = row; rx[r] = x2a[row]; ry[r] = y2a[row]; rb[r] = row / 784;
    }
    #pragma unroll
    for (int tc = 0; tc < 4; ++tc) {
      int col = C * 128 + wc + tc * 16 + lr;
      int cxv = xd[col], cyv = yd[col], cb = col / 784;  // xd vs xy2[0], yd vs xy2[1]
      #pragma unroll
      for (int r = 0; r < 4; ++r) {
        int dx = cxv - rx[r], dy = cyv - ry[r];
        int dis2 = dx * dx + dy * dy + (cb != rb[r] ? 9 : 0);
        float v = acc[tr][tc][r];
        if (dis2 < 9) v = 0.0f;
        __builtin_nontemporal_store(v, &out[SCORES_OFF + (size_t)rows[r] * NCOLS + 13 + col]);
      }
    }
  }
}

extern "C" void kernel_launch(void* const* d_in, const int* in_sizes, int n_in,
                              void* d_out, int out_size, void* d_ws, size_t ws_size,
                              hipStream_t stream) {
  const float* des1 = (const float*)d_in[0];
  const float* det1 = (const float*)d_in[1];
  const float* qlt1 = (const float*)d_in[2];
  const float* des2 = (const float*)d_in[3];
  const float* det2 = (const float*)d_in[4];
  const float* qlt2 = (const float*)d_in[5];
  const float* aflow = (const float*)d_in[6];
  float* out = (float*)d_out;

  // workspace layout (16B-aligned blocks)
  char* ws = (char*)d_ws;
  int* x2a = (int*)ws;                       // NS
  int* y2a = x2a + NS;
  int* xd  = y2a + NS;
  int* yd  = xd + NS;
  float* qlt1v = (float*)(yd + NS);          // NS
  float* A_f32 = qlt1v + NS + NS;            // NS*128 (extra NS pad keeps 16B align)
  u16* A_bf16 = (u16*)(A_f32 + (size_t)NS * 128);  // NS*128
  u16* D_bf16 = A_bf16 + (size_t)NS * 128;         // NS*128

  // K1: sample + fused gather + labels zeroing (no hipMemsetAsync)
  sample_gather_zero_kernel<<<3136 + ZBLK, 256, 0, stream>>>(
      det1, det2, aflow, qlt1, des1, des2,
      x2a, y2a, xd, yd, qlt1v, A_f32, A_bf16, D_bf16, out);

  // K2: small scores (+labels col0, qlt) co-scheduled with dscores GEMM
  scores_kernel<<<1568 + 49 * 49, 256, 0, stream>>>(
      A_bf16, D_bf16, des2, qlt2, A_f32, qlt1v, x2a, y2a, xd, yd, out);
}

// Round 2
// 729.614 us; speedup vs baseline: 1.1128x; 1.1128x over previous
//
#include <hip/hip_runtime.h>

typedef unsigned short u16;
typedef unsigned int u32;
typedef __bf16 bf16x8 __attribute__((ext_vector_type(8)));
typedef float f32x4 __attribute__((ext_vector_type(4)));
typedef unsigned int u32x4 __attribute__((ext_vector_type(4)));

// Problem constants (B=8, D=128, H=W=256, border=16, cell=8)
#define NS 6272              // samples per image set (8*28*28)
#define NCOLS 6285           // 1 + 12 + 6272
#define SCORES_OFF 0LL
#define LABELS_OFF 39419520LL
#define MASK_OFF   78839040LL
#define QLT_OFF    78845312LL

#define ZBLK 2048            // zeroing blocks in K1 grid
#define LBL_F4 9854880       // NS*NCOLS/4 (labels region in float4s, exact)
#define TBLK 16384           // transpose blocks (8 b * 256 y * 8 x-tiles)
#define DES2T_BYTES 268435456ull   // 8*256*256*128*4

// Unified offset table: [0,29) = pos (i^2+j^2<=9), [29,41) = neg ring.
// OFFX -> x (W) offset, OFFY -> y (H) offset.
__constant__ int OFFX[41] = {-3,-2,-2,-2,-2,-2,-1,-1,-1,-1,-1, 0,0,0,0,0,0,0, 1,1,1,1,1, 2,2,2,2,2, 3,
                             -8,-6,-6,-4,-4, 0,0, 4,4, 6,6, 8};
__constant__ int OFFY[41] = { 0,-2,-1, 0, 1, 2,-2,-1, 0, 1, 2,-3,-2,-1,0,1,2,3,-2,-1,0,1,2,-2,-1,0,1,2, 0,
                              0,-4, 4,-6, 6,-8,8,-6,6,-4,4, 0};

__device__ inline u16 f2bf(float f) {
  u32 u = __float_as_uint(f);
  u = (u + 0x7FFFu + ((u >> 16) & 1u)) >> 16;  // RNE (inputs have no NaN)
  return (u16)u;
}

// K1: heterogeneous grid.
//  [0,3136)        : one wave per 8x8 cell -> butterfly argmax -> fused
//                    descriptor gather + per-sample bookkeeping.
//  [3136,5184)     : zero the labels output region (replaces hipMemsetAsync).
//  [5184,5184+TBLK): (USE_T only) transpose des2 [b][c][y][x] -> des2T
//                    [b][y][x][c] f32, 32-x-wide tiles via LDS. BW-bound work
//                    that overlaps the latency-bound gathers.
// NOTE the reference's coordinate SWAP: _sample returns (b,x,y) unpacked as
// (b, y1, x1) -> all gathers at sample points use row=X (W-coord of max),
// col=Y (H-coord of max).
template <int USE_T>
__global__ __launch_bounds__(256) void k1_kernel(
    const float* __restrict__ det1, const float* __restrict__ det2,
    const float* __restrict__ aflow, const float* __restrict__ qlt1,
    const float* __restrict__ des1, const float* __restrict__ des2,
    int* __restrict__ x2a, int* __restrict__ y2a,
    int* __restrict__ xd, int* __restrict__ yd,
    float* __restrict__ qlt1v,
    float* __restrict__ A_f32, u16* __restrict__ A_bf16, u16* __restrict__ D_bf16,
    float* __restrict__ des2T, float* __restrict__ out) {
  __shared__ float sm[32 * 129];   // transpose tile (pad 1 word: bank-clean)
  if (USE_T && blockIdx.x >= 5184) {
    int tb = blockIdx.x - 5184;
    int b = tb >> 11, y = (tb >> 3) & 255, x0 = (tb & 7) * 32;
    int t = threadIdx.x;
    int xi = t & 31, cb = t >> 5;
    #pragma unroll
    for (int p = 0; p < 16; ++p) {
      int c = cb + p * 8;
      sm[xi * 129 + c] = des2[(((size_t)(b * 128 + c)) << 16) + (y << 8) + x0 + xi];
    }
    __syncthreads();
    int c2 = t & 127, xb = t >> 7;
    size_t obase = ((((size_t)b << 16) + (y << 8) + x0) << 7);
    #pragma unroll
    for (int q = 0; q < 16; ++q) {
      int xw = xb + 2 * q;
      __builtin_nontemporal_store(sm[xw * 129 + c2],
                                  &des2T[obase + ((size_t)xw << 7) + c2]);
    }
    return;
  }
  if (blockIdx.x >= 3136) {
    // zero labels region, nontemporal float4 streaming stores
    size_t t = (size_t)(blockIdx.x - 3136) * 256 + threadIdx.x;
    f32x4* p = (f32x4*)(out + LABELS_OFF);
    f32x4 z = {0.0f, 0.0f, 0.0f, 0.0f};
    for (size_t i = t; i < (size_t)LBL_F4; i += (size_t)ZBLK * 256)
      __builtin_nontemporal_store(z, p + i);
    return;
  }
  int isDet2 = (blockIdx.x >= 1568);
  int cell = (blockIdx.x - (isDet2 ? 1568 : 0)) * 4 + (threadIdx.x >> 6);
  int l = threadIdx.x & 63;
  int b = cell / 784, rem = cell % 784;
  int cy = rem / 28, cx = rem % 28;
  int y = 16 + cy * 8 + (l >> 3), x = 16 + cx * 8 + (l & 7);
  const float* det = isDet2 ? det2 : det1;
  float v = det[((size_t)b << 16) + (y << 8) + x];
  int idx = l;
  // butterfly: every lane ends with (max, lowest index on ties)
  #pragma unroll
  for (int off = 1; off < 64; off <<= 1) {
    float ov = __shfl_xor(v, off);
    int oi = __shfl_xor(idx, off);
    if (ov > v || (ov == v && oi < idx)) { v = ov; idx = oi; }
  }
  int ii = idx >> 3, jj = idx & 7;
  int X = 16 + cx * 8 + jj;   // W-coordinate of cell max
  int Y = 16 + cy * 8 + ii;   // H-coordinate of cell max
  if (!isDet2) {
    if (l == 0) {
      // reference: y1 = X (row index), x1 = Y (col index)
      float ax = aflow[((size_t)(b * 2) << 16) + (X << 8) + Y];
      float ay = aflow[((size_t)(b * 2 + 1) << 16) + (X << 8) + Y];
      int xx = (int)(ax + 0.5f);   // trunc after +0.5, matches astype(int32)
      int yy = (int)(ay + 0.5f);
      x2a[cell] = xx; y2a[cell] = yy;
      out[MASK_OFF + cell] = (xx >= 0 && yy >= 0 && xx < 256 && yy < 256) ? 1.0f : 0.0f;
      qlt1v[cell] = qlt1[((size_t)b << 16) + (X << 8) + Y];
    }
    // gather des1[b, :, X, Y]: 2 channels per lane (c = l and c = l+64)
    const float* p = des1 + (((size_t)b * 128) << 16) + (X << 8) + Y;
    float v0 = p[(size_t)l << 16];
    float v1 = p[(size_t)(l + 64) << 16];
    A_f32[(size_t)cell * 128 + l] = v0;
    A_f32[(size_t)cell * 128 + l + 64] = v1;
    A_bf16[(size_t)cell * 128 + l] = f2bf(v0);
    A_bf16[(size_t)cell * 128 + l + 64] = f2bf(v1);
  } else {
    if (l == 0) {
      // reference: yd = X (row index), xd = Y (col index)
      yd[cell] = X; xd[cell] = Y;
    }
    // distr = des2[bd, :, yd, xd]
    const float* p = des2 + (((size_t)b * 128) << 16) + (X << 8) + Y;
    D_bf16[(size_t)cell * 128 + l] = f2bf(p[(size_t)l << 16]);
    D_bf16[(size_t)cell * 128 + l + 64] = f2bf(p[(size_t)(l + 64) << 16]);
  }
}

// K2: heterogeneous blocks.
//  blockIdx.x <  1568 : small-scores + labels col0 + qlt.
//    USE_T: octet-cooperative coalesced reads from channel-last des2T
//           (8 lanes x 4 f32x4 per candidate, shuffle-reduced).
//    else : per-lane channel-major loop over des2 (fallback).
//  blockIdx.x >= 1568 : dscores GEMM tile (bf16 MFMA 16x16x32, 128x128 tile),
//    XOR-swizzled LDS (conflict-free ds_read_b128), fused distance-mask,
//    epilogue staged through LDS -> 256B-contiguous full-line stores.
template <int USE_T>
__global__ __launch_bounds__(256, 2) void k2_kernel(
    const u16* __restrict__ A, const u16* __restrict__ Bm,
    const float* __restrict__ des2, const float* __restrict__ qlt2,
    const float* __restrict__ A_f32, const float* __restrict__ qlt1v,
    const int* __restrict__ x2a, const int* __restrict__ y2a,
    const int* __restrict__ xd, const int* __restrict__ yd,
    const float* __restrict__ des2T, float* __restrict__ out) {
  __shared__ __align__(16) char smem[66560];   // max(2*32KB bf16 tiles, 128x130 f32)
  int tid = threadIdx.x;
  if (blockIdx.x < 1568) {
    int n = blockIdx.x * 4 + (tid >> 6);
    int l = tid & 63;
    int b = n / 784;
    int x2 = x2a[n], y2 = y2a[n];
    if (USE_T) {
      // octet o = l&7 covers channels {o*4..} in 4 f32x4 chunks; candidate per octet
      const f32x4* av = (const f32x4*)(A_f32 + (size_t)n * 128);
      int o = l & 7;
      f32x4 a0 = av[o], a1 = av[o + 8], a2 = av[o + 16], a3 = av[o + 24];
      float best = -1e30f; int bestk = 63;
      #pragma unroll
      for (int pass = 0; pass < 6; ++pass) {
        int k = pass * 8 + (l >> 3);
        int kc = min(k, 40);
        int xc = min(max(x2 + OFFX[kc], 0), 255);
        int yc = min(max(y2 + OFFY[kc], 0), 255);
        const f32x4* d = (const f32x4*)(des2T + ((((size_t)b << 16) + (yc << 8) + xc) << 7));
        f32x4 d0 = d[o], d1 = d[o + 8], d2v = d[o + 16], d3 = d[o + 24];
        float s = a0[0]*d0[0] + a0[1]*d0[1] + a0[2]*d0[2] + a0[3]*d0[3]
                + a1[0]*d1[0] + a1[1]*d1[1] + a1[2]*d1[2] + a1[3]*d1[3]
                + a2[0]*d2v[0] + a2[1]*d2v[1] + a2[2]*d2v[2] + a2[3]*d2v[3]
                + a3[0]*d3[0] + a3[1]*d3[1] + a3[2]*d3[2] + a3[3]*d3[3];
        s += __shfl_xor(s, 1); s += __shfl_xor(s, 2); s += __shfl_xor(s, 4);
        if (k <= 28) {
          if (s > best) { best = s; bestk = k; }   // k ascending per octet -> first-occurrence kept
        } else if (k <= 40 && o == 0) {
          out[SCORES_OFF + (size_t)n * NCOLS + 1 + (k - 29)] = s;
        }
      }
      #pragma unroll
      for (int off = 8; off < 64; off <<= 1) {
        float ov = __shfl_xor(best, off);
        int ok = __shfl_xor(bestk, off);
        if (ov > best || (ov == best && ok < bestk)) { best = ov; bestk = ok; }
      }
      if (l == 0) {
        out[SCORES_OFF + (size_t)n * NCOLS] = best;
        out[LABELS_OFF + (size_t)n * NCOLS] = 1.0f;
        int sx = min(max(x2 + OFFX[bestk], 0), 255);
        int sy = min(max(y2 + OFFY[bestk], 0), 255);
        out[QLT_OFF + n] = (qlt1v[n] + qlt2[((size_t)b << 16) + (sy << 8) + sx]) * 0.5f;
      }
    } else {
      // fallback: per-lane candidate, channel-major loop
      int ox = 0, oy = 0;
      if (l < 41) { ox = OFFX[l]; oy = OFFY[l]; }
      int xc = min(max(x2 + ox, 0), 255);
      int yc = min(max(y2 + oy, 0), 255);
      const float* d2 = des2 + ((size_t)b << 23) + ((size_t)yc << 8) + xc;
      const float* ar = A_f32 + (size_t)n * 128;
      float acc = 0.0f;
      #pragma unroll 16
      for (int c = 0; c < 128; ++c) acc += ar[c] * d2[(size_t)c << 16];
      if (l >= 29 && l < 41) out[SCORES_OFF + (size_t)n * NCOLS + 1 + (l - 29)] = acc;
      float v = (l < 29) ? acc : -1e30f;
      int idx = l;
      #pragma unroll
      for (int off = 32; off; off >>= 1) {
        float ov = __shfl_down(v, off);
        int oi = __shfl_down(idx, off);
        if (ov > v || (ov == v && oi < idx)) { v = ov; idx = oi; }
      }
      if (l == 0) {
        out[SCORES_OFF + (size_t)n * NCOLS] = v;
        out[LABELS_OFF + (size_t)n * NCOLS] = 1.0f;
        int sx = min(max(x2 + OFFX[idx], 0), 255);
        int sy = min(max(y2 + OFFY[idx], 0), 255);
        out[QLT_OFF + n] = (qlt1v[n] + qlt2[((size_t)b << 16) + (sy << 8) + sx]) * 0.5f;
      }
    }
    return;
  }
  // ---- dscores GEMM: C[n,m] = sum_k A[n,k]*D[m,k] ----
  u16* As = (u16*)smem;          // [128][128] u16, XOR-swizzled 16B chunks
  u16* Bs = As + 16384;
  int bi = blockIdx.x - 1568;
  int R = bi / 49, C = bi % 49;
  const u32x4* gA = (const u32x4*)(A + (size_t)R * 16384);
  const u32x4* gB = (const u32x4*)(Bm + (size_t)C * 16384);
  u32x4* wA = (u32x4*)As; u32x4* wB = (u32x4*)Bs;
  #pragma unroll
  for (int p = 0; p < 8; ++p) {
    int i = tid + p * 256;
    int r = i >> 4, cc = i & 15;
    int sw = r * 16 + (cc ^ (r & 7));   // chunk XOR-swizzle: conflict-free b128 reads
    wA[sw] = gA[i];
    wB[sw] = gB[i];
  }
  __syncthreads();
  int l = tid & 63, w = tid >> 6;
  int lr = l & 15, lq = l >> 4;
  int wr = (w & 1) * 64, wc = (w >> 1) * 64;
  int sw7 = lr & 7;                     // (row & 7) for all fragment rows
  f32x4 acc[4][4] = {};
  #pragma unroll
  for (int kk = 0; kk < 4; ++kk) {
    bf16x8 af[4], bfr[4];
    int cc = ((kk * 4 + lq) ^ sw7) * 8;
    #pragma unroll
    for (int t = 0; t < 4; ++t) {
      af[t]  = *(const bf16x8*)&As[(wr + t * 16 + lr) * 128 + cc];
      bfr[t] = *(const bf16x8*)&Bs[(wc + t * 16 + lr) * 128 + cc];
    }
    #pragma unroll
    for (int tr = 0; tr < 4; ++tr)
      #pragma unroll
      for (int tc = 0; tc < 4; ++tc)
        acc[tr][tc] = __builtin_amdgcn_mfma_f32_16x16x32_bf16(af[tr], bfr[tc], acc[tr][tc], 0, 0, 0);
  }
  __syncthreads();                      // As/Bs dead; reuse as f32 C-tile
  float* Cs = (float*)smem;             // [128][130] f32 (pad 2: bank-clean)
  #pragma unroll
  for (int tr = 0; tr < 4; ++tr) {
    int rows[4], rx[4], ry[4], rb[4];
    #pragma unroll
    for (int r = 0; r < 4; ++r) {
      int row = R * 128 + wr + tr * 16 + lq * 4 + r;
      rows[r] = row; rx[r] = x2a[row]; ry[r] = y2a[row]; rb[r] = row / 784;
    }
    #pragma unroll
    for (int tc = 0; tc < 4; ++tc) {
      int col = C * 128 + wc + tc * 16 + lr;
      int cxv = xd[col], cyv = yd[col], cb = col / 784;
      #pragma unroll
      for (int r = 0; r < 4; ++r) {
        int dx = cxv - rx[r], dy = cyv - ry[r];
        int dis2 = dx * dx + dy * dy + (cb != rb[r] ? 9 : 0);
        float v = acc[tr][tc][r];
        if (dis2 < 9) v = 0.0f;
        Cs[(wr + tr * 16 + lq * 4 + r) * 130 + wc + tc * 16 + lr] = v;
      }
    }
  }
  __syncthreads();
  // store: 128 lanes cover one 512B row-segment -> full-line streaming writes
  size_t base = (size_t)R * 128 * NCOLS + 13 + (size_t)C * 128;
  int rr = tid >> 7, c = tid & 127;
  #pragma unroll 8
  for (int p = 0; p < 64; ++p) {
    int row = rr + 2 * p;
    __builtin_nontemporal_store(Cs[row * 130 + c],
                                &out[SCORES_OFF + base + (size_t)row * NCOLS + c]);
  }
}

extern "C" void kernel_launch(void* const* d_in, const int* in_sizes, int n_in,
                              void* d_out, int out_size, void* d_ws, size_t ws_size,
                              hipStream_t stream) {
  const float* des1 = (const float*)d_in[0];
  const float* det1 = (const float*)d_in[1];
  const float* qlt1 = (const float*)d_in[2];
  const float* des2 = (const float*)d_in[3];
  const float* det2 = (const float*)d_in[4];
  const float* qlt2 = (const float*)d_in[5];
  const float* aflow = (const float*)d_in[6];
  float* out = (float*)d_out;

  // transpose path needs des2T (256MB) + side arrays (~6.3MB)
  const size_t need = DES2T_BYTES + 6598144ull;
  const bool useT = (ws_size >= need);

  char* ws = (char*)d_ws;
  float* des2T = (float*)ws;
  char* wsb = ws + (useT ? DES2T_BYTES : 0);
  int* x2a = (int*)wsb;                      // NS each
  int* y2a = x2a + NS;
  int* xd  = y2a + NS;
  int* yd  = xd + NS;
  float* qlt1v = (float*)(yd + NS);          // NS
  float* A_f32 = qlt1v + 2 * NS;             // NS*128 (NS pad keeps 16B align)
  u16* A_bf16 = (u16*)(A_f32 + (size_t)NS * 128);  // NS*128
  u16* D_bf16 = A_bf16 + (size_t)NS * 128;         // NS*128

  if (useT) {
    k1_kernel<1><<<3136 + ZBLK + TBLK, 256, 0, stream>>>(
        det1, det2, aflow, qlt1, des1, des2,
        x2a, y2a, xd, yd, qlt1v, A_f32, A_bf16, D_bf16, des2T, out);
    k2_kernel<1><<<1568 + 49 * 49, 256, 0, stream>>>(
        A_bf16, D_bf16, des2, qlt2, A_f32, qlt1v, x2a, y2a, xd, yd, des2T, out);
  } else {
    k1_kernel<0><<<3136 + ZBLK, 256, 0, stream>>>(
        det1, det2, aflow, qlt1, des1, des2,
        x2a, y2a, xd, yd, qlt1v, A_f32, A_bf16, D_bf16, des2T, out);
    k2_kernel<0><<<1568 + 49 * 49, 256, 0, stream>>>(
        A_bf16, D_bf16, des2, qlt2, A_f32, qlt1v, x2a, y2a, xd, yd, des2T, out);
  }
}